// Round 6
// baseline (220.075 us; speedup 1.0000x reference)
//
#include <hip/hip_runtime.h>
#include <hip/hip_bf16.h>

// Gram-trick pipeline (B=8, C=512, T=4096, SCALE=512):
//   sx[b,c]   = sum_t x[b,c,t]           (fused into streaming convert)
//   G[b]      = x_b x_b^T                (bf16 MFMA, split-K=4 + reduce)   [symmetric]
//   middle v2 : per 16-row strip: tmp = Wqk_strip*G (NT via symmetry);
//               scores = tmp*Wv^T + biases; softmax_v + pb;  M_strip = p*Wv
//               256 blocks (XCD chunk = one batch), dbuf K=32 panels
//   out[b]    = M[b] x_b + pb            (NN: B=xh via subtiled LDS + ds_read_b64_tr_b16)

#define BB 8
#define CC 512
#define TT 4096

typedef __attribute__((ext_vector_type(8))) short bf16x8;
typedef __attribute__((ext_vector_type(4))) short bf16x4;
typedef __attribute__((ext_vector_type(4))) float f32x4;

__device__ __forceinline__ void gload_lds16(const void* g, void* l) {
  __builtin_amdgcn_global_load_lds((const __attribute__((address_space(1))) void*)g,
                                   (__attribute__((address_space(3))) void*)l,
                                   16, 0, 0);
}
__device__ __forceinline__ float bf2f(short u) {
  return __uint_as_float(((unsigned)(unsigned short)u) << 16);
}
__device__ __forceinline__ unsigned short f2bf(float f) {
  return __builtin_bit_cast(unsigned short, __float2bfloat16(f));
}

// ---- streaming convert x -> bf16 [c,t] + fused row-sum ---------------------
__global__ __launch_bounds__(256)
void convert_stream_kernel(const float* __restrict__ x, __hip_bfloat16* __restrict__ xh,
                           float* __restrict__ sx)
{
  const int gid = blockIdx.x * 256 + threadIdx.x;
#pragma unroll
  for (int it = 0; it < 4; it++) {
    const int chunk = it * 524288 + gid;          // 8-float chunk index
    const size_t base = (size_t)chunk * 8;
    const float4 a = *(const float4*)&x[base];
    const float4 c = *(const float4*)&x[base + 4];
    bf16x8 h;
    h[0] = (short)f2bf(a.x); h[1] = (short)f2bf(a.y);
    h[2] = (short)f2bf(a.z); h[3] = (short)f2bf(a.w);
    h[4] = (short)f2bf(c.x); h[5] = (short)f2bf(c.y);
    h[6] = (short)f2bf(c.z); h[7] = (short)f2bf(c.w);
    *(bf16x8*)&xh[base] = h;
    float s = ((a.x + a.y) + (a.z + a.w)) + ((c.x + c.y) + (c.z + c.w));
#pragma unroll
    for (int off = 32; off; off >>= 1) s += __shfl_xor(s, off);
    if ((threadIdx.x & 63) == 0) atomicAdd(&sx[chunk >> 9], s);  // wave-uniform row
  }
}

// ---- weights -> bf16 (+WvT) AND ta/tb dot products (grid 3072) -------------
__global__ __launch_bounds__(256)
void prep_w_kernel(const float* __restrict__ Wqk, const float* __restrict__ Wv,
                   const float* __restrict__ sx,
                   __hip_bfloat16* __restrict__ Wqkh, __hip_bfloat16* __restrict__ Wvh,
                   __hip_bfloat16* __restrict__ WvT,
                   float* __restrict__ ta, float* __restrict__ tb)
{
  const int blk = blockIdx.x;
  if (blk < 1024) {
    int i = blk * 256 + threadIdx.x;  // < 512*512
    Wqkh[i] = __float2bfloat16(Wqk[i]);
    float wv = Wv[i];
    Wvh[i] = __float2bfloat16(wv);
    WvT[(i & 511) * 512 + (i >> 9)] = __float2bfloat16(wv);
  } else {
    int wid = threadIdx.x >> 6, lane = threadIdx.x & 63;
    int gid = (blk - 1024) * 4 + wid;  // [0, 8192) = 2 * 8 * 512 jobs
    int which = gid >> 12;
    int rem = gid & 4095;
    int b = rem >> 9, j = rem & 511;
    const float* W = which ? Wv : Wqk;
    float s = 0.f;
#pragma unroll
    for (int i2 = 0; i2 < 8; i2++) {
      int c = lane + i2 * 64;
      s += W[j * 512 + c] * sx[b * 512 + c];
    }
#pragma unroll
    for (int off = 32; off; off >>= 1) s += __shfl_xor(s, off);
    if (lane == 0) (which ? tb : ta)[b * 512 + j] = s;
  }
}

// ---- NT GEMM template: C = A[M,K] B[N,K]^T, 2-phase pipelined dbuf ---------
template <int BM, int BN, int EPI>
__global__ __launch_bounds__(256)
void gemm_nt_kernel(const __hip_bfloat16* __restrict__ A, long strideA, int ldA,
                    const __hip_bfloat16* __restrict__ B, long strideB, int ldB,
                    void* __restrict__ C, long strideC, int ldC,
                    int Kslice, int nslices)
{
  constexpr int FM = BM / 32, FN = BN / 32;
  const int tid = threadIdx.x, lane = tid & 63, wid = tid >> 6;

  const int gx = gridDim.x, gy = gridDim.y;
  const int lin = blockIdx.x + gx * (blockIdx.y + gy * blockIdx.z);
  const int nwg = gx * gy * (int)gridDim.z;
  const int lin2 = (lin & 7) * (nwg >> 3) + (lin >> 3);
  const int tn = lin2 % gx;
  const int r1 = lin2 / gx;
  const int tm = r1 % gy;
  const int z  = r1 / gy;
  const int b  = z / nslices;
  const int ks = z - b * nslices;

  const __hip_bfloat16* Ab = A + (size_t)b * strideA + (size_t)(tm * BM) * ldA + (size_t)ks * Kslice;
  const __hip_bfloat16* Bb = B + (size_t)b * strideB + (size_t)(tn * BN) * ldB + (size_t)ks * Kslice;

  __shared__ __align__(16) __hip_bfloat16 sA[2][BM * 64];
  __shared__ __align__(16) __hip_bfloat16 sB[2][BN * 64];

  const int wr = wid >> 1, wc = wid & 1;

  f32x4 acc[FM][FN];
#pragma unroll
  for (int m = 0; m < FM; m++)
#pragma unroll
    for (int n = 0; n < FN; n++) acc[m][n] = (f32x4){0.f, 0.f, 0.f, 0.f};

  auto stage = [&](int buf, int k0) {
#pragma unroll
    for (int i = 0; i < BM / 32; i++) {
      int e = tid * 8 + i * 2048;
      int row = e >> 6, colg = (e & 63) ^ ((row & 7) << 3);
      gload_lds16(Ab + (size_t)row * ldA + k0 + colg, &sA[buf][wid * 512 + i * 2048]);
    }
#pragma unroll
    for (int i = 0; i < BN / 32; i++) {
      int e = tid * 8 + i * 2048;
      int row = e >> 6, colg = (e & 63) ^ ((row & 7) << 3);
      gload_lds16(Bb + (size_t)row * ldB + k0 + colg, &sB[buf][wid * 512 + i * 2048]);
    }
  };

  stage(0, 0);
  __syncthreads();
  const int nsteps = Kslice >> 6;
  for (int s = 0; s < nsteps; s++) {
    if (s + 1 < nsteps) stage((s + 1) & 1, (s + 1) << 6);
    const __hip_bfloat16* cA = sA[s & 1];
    const __hip_bfloat16* cB = sB[s & 1];
#pragma unroll
    for (int ks2 = 0; ks2 < 2; ks2++) {
      bf16x8 af[FM], bfv[FN];
      const int kb = ks2 * 32 + (lane >> 4) * 8;
#pragma unroll
      for (int m = 0; m < FM; m++) {
        int row = wr * (BM / 2) + m * 16 + (lane & 15);
        af[m] = *(const bf16x8*)&cA[row * 64 + (kb ^ ((row & 7) << 3))];
      }
#pragma unroll
      for (int n = 0; n < FN; n++) {
        int row = wc * (BN / 2) + n * 16 + (lane & 15);
        bfv[n] = *(const bf16x8*)&cB[row * 64 + (kb ^ ((row & 7) << 3))];
      }
#pragma unroll
      for (int m = 0; m < FM; m++)
#pragma unroll
        for (int n = 0; n < FN; n++)
          acc[m][n] = __builtin_amdgcn_mfma_f32_16x16x32_bf16(af[m], bfv[n], acc[m][n], 0, 0, 0);
    }
    __syncthreads();
  }

  // epilogue (bf16 store). C/D: col = lane&15, row = (lane>>4)*4 + reg
  const int rb = tm * BM + wr * (BM / 2) + ((lane >> 4) << 2);
  const int cb = tn * BN + wc * (BN / 2) + (lane & 15);
  __hip_bfloat16* Cb = (__hip_bfloat16*)C + (size_t)z * strideC;
#pragma unroll
  for (int m = 0; m < FM; m++)
#pragma unroll
    for (int n = 0; n < FN; n++)
#pragma unroll
      for (int r = 0; r < 4; r++) {
        int row = rb + m * 16 + r, col = cb + n * 16;
        Cb[(size_t)row * ldC + col] = __float2bfloat16(acc[m][n][r]);
      }
}

// ---- reduce split-K bf16 partials -> bf16 G --------------------------------
__global__ __launch_bounds__(256)
void reduce_g_kernel(const short* __restrict__ Gpart, short* __restrict__ Gb)
{
  const int idx = (blockIdx.x * 256 + threadIdx.x) * 8;  // < BB*262144
  const int b = idx >> 18, i = idx & 262143;
  const short* base = Gpart + ((size_t)(b * 4) << 18) + i;
  float s[8];
#pragma unroll
  for (int q = 0; q < 8; q++) s[q] = 0.f;
#pragma unroll
  for (int ks = 0; ks < 4; ks++) {
    bf16x8 v = *(const bf16x8*)(base + ((size_t)ks << 18));
#pragma unroll
    for (int q = 0; q < 8; q++) s[q] += bf2f(v[q]);
  }
  bf16x8 o;
#pragma unroll
  for (int q = 0; q < 8; q++) o[q] = (short)f2bf(s[q]);
  *(bf16x8*)(Gb + ((size_t)b << 18) + i) = o;
}

// ---- middle v2: 256 blocks, 16-row strips, dbuf K=32 panels ----------------
// XCD chunk (lin&7)*32 + lin>>3 => each XCD owns one batch (L2-resident set).
// stage1: tmp = Wqk_strip * G (NT, G symmetric); stage2: scores = tmp*Wv^T + biases;
// softmax over v + pb; stage3: M_strip = p * Wv (NT with WvT).
__global__ __launch_bounds__(256)
void middle_kernel(const __hip_bfloat16* __restrict__ Gh,
                   const __hip_bfloat16* __restrict__ Wqkh,
                   const __hip_bfloat16* __restrict__ Wvh,
                   const __hip_bfloat16* __restrict__ WvT,
                   const float* __restrict__ bqk, const float* __restrict__ bv,
                   const float* __restrict__ ta, const float* __restrict__ tb,
                   __hip_bfloat16* __restrict__ Mm, float* __restrict__ pb)
{
  __shared__ __align__(16) __hip_bfloat16 sW[16 * 512];      // Wqk strip (swizzled)
  __shared__ __align__(16) __hip_bfloat16 sT[16 * 512];      // tmp, then p (swizzled)
  __shared__ __align__(16) __hip_bfloat16 sB[2][512 * 32];   // dbuf K=32 panels
  __shared__ float red1[4][16], red2[4][16], red3[4][16];

  const int tid = threadIdx.x, lane = tid & 63, wid = tid >> 6;
  const int lin = blockIdx.x;
  const int lin2 = (lin & 7) * 32 + (lin >> 3);   // XCD chunk = one batch
  const int strip = lin2 & 31, b = lin2 >> 5;
  const __hip_bfloat16* Ghb = Gh + (size_t)b * 262144;

  // stage Wqk strip [16][512]: linear dest, inverse-swizzled source
#pragma unroll
  for (int i = 0; i < 4; i++) {
    int row = i * 4 + wid;
    int scol = 8 * (lane ^ (row & 7));
    gload_lds16(Wqkh + (size_t)(strip * 16 + row) * 512 + scol, &sW[i * 2048 + wid * 512]);
  }

  // B panel [512 N][32 K], swizzle colblk ^ (row&3)
  auto stageB = [&](int buf, const __hip_bfloat16* Bsrc, int k0) {
#pragma unroll
    for (int i = 0; i < 8; i++) {
      int r = i * 64 + wid * 16 + (lane >> 2);
      int scol = k0 + 8 * ((lane & 3) ^ (r & 3));
      gload_lds16(Bsrc + (size_t)r * 512 + scol, &sB[buf][i * 2048 + wid * 512]);
    }
  };

  const int arow = lane & 15;
  const int asw = (arow & 7) << 3;
  f32x4 acc[8];

#define RUN_STAGE(BSRC, SX)                                                     \
  {                                                                             \
    _Pragma("unroll") for (int n = 0; n < 8; n++) acc[n] = (f32x4){0.f,0.f,0.f,0.f}; \
    stageB(0, BSRC, 0);                                                         \
    __syncthreads();                                                            \
    for (int t = 0; t < 16; t++) {                                              \
      if (t < 15) stageB((t + 1) & 1, BSRC, (t + 1) * 32);                      \
      const __hip_bfloat16* cB = sB[t & 1];                                     \
      const int kq = t * 32 + (lane >> 4) * 8;                                  \
      bf16x8 af = *(const bf16x8*)&SX[arow * 512 + (kq ^ asw)];                 \
      const int kb = (lane >> 4) * 8;                                           \
      _Pragma("unroll") for (int n = 0; n < 8; n++) {                           \
        int brow = wid * 128 + n * 16 + (lane & 15);                            \
        bf16x8 bfv = *(const bf16x8*)&cB[brow * 32 + (kb ^ ((brow & 3) << 3))]; \
        acc[n] = __builtin_amdgcn_mfma_f32_16x16x32_bf16(af, bfv, acc[n], 0, 0, 0); \
      }                                                                         \
      __syncthreads();                                                          \
    }                                                                           \
  }

  // ---- stage 1: tmp = Wqk_strip * G
  RUN_STAGE(Ghb, sW);
#pragma unroll
  for (int n = 0; n < 8; n++)
#pragma unroll
    for (int r = 0; r < 4; r++) {
      int lr = ((lane >> 4) << 2) + r;
      int col = wid * 128 + n * 16 + (lane & 15);
      sT[lr * 512 + (col ^ ((lr & 7) << 3))] = __float2bfloat16(acc[n][r]);
    }
  __syncthreads();

  // ---- stage 2: scores = tmp * Wv^T
  RUN_STAGE(Wvh, sT);

  const float* tab = ta + b * 512;
  const float* tbb = tb + b * 512;
  float bvc[8], tbc[8];
#pragma unroll
  for (int n = 0; n < 8; n++) {
    int col = wid * 128 + n * 16 + (lane & 15);
    bvc[n] = bv[col]; tbc[n] = tbb[col];
  }
  float bq[4], tar[4];
#pragma unroll
  for (int r = 0; r < 4; r++) {
    int gr = strip * 16 + ((lane >> 4) << 2) + r;
    bq[r] = bqk[gr]; tar[r] = tab[gr];
  }
#pragma unroll
  for (int n = 0; n < 8; n++)
#pragma unroll
    for (int r = 0; r < 4; r++)
      acc[n][r] = (acc[n][r] + bq[r] * tbc[n] + tar[r] * bvc[n]
                   + 4096.0f * bq[r] * bvc[n]) * (1.0f / 512.0f);

  // row-max: in-lane over n, 16-lane group over cols, cross-wave via LDS
#pragma unroll
  for (int r = 0; r < 4; r++) {
    float v = acc[0][r];
#pragma unroll
    for (int n = 1; n < 8; n++) v = fmaxf(v, acc[n][r]);
#pragma unroll
    for (int off = 1; off < 16; off <<= 1) v = fmaxf(v, __shfl_xor(v, off));
    if ((lane & 15) == 0) red1[wid][((lane >> 4) << 2) + r] = v;
  }
  __syncthreads();
  float mx[4];
#pragma unroll
  for (int r = 0; r < 4; r++) {
    int lr = ((lane >> 4) << 2) + r;
    mx[r] = fmaxf(fmaxf(red1[0][lr], red1[1][lr]), fmaxf(red1[2][lr], red1[3][lr]));
  }
#pragma unroll
  for (int r = 0; r < 4; r++) {
    float s = 0.f, pp = 0.f;
#pragma unroll
    for (int n = 0; n < 8; n++) {
      float e = __expf(acc[n][r] - mx[r]);
      acc[n][r] = e;
      s += e; pp += e * bvc[n];
    }
#pragma unroll
    for (int off = 1; off < 16; off <<= 1) { s += __shfl_xor(s, off); pp += __shfl_xor(pp, off); }
    if ((lane & 15) == 0) {
      red2[wid][((lane >> 4) << 2) + r] = s;
      red3[wid][((lane >> 4) << 2) + r] = pp;
    }
  }
  __syncthreads();
  float inv[4];
#pragma unroll
  for (int r = 0; r < 4; r++) {
    int lr = ((lane >> 4) << 2) + r;
    float sum = red2[0][lr] + red2[1][lr] + red2[2][lr] + red2[3][lr];
    inv[r] = 1.0f / sum;
    if (wid == 0 && (lane & 15) == 0)
      pb[b * 512 + strip * 16 + lr] =
          (red3[0][lr] + red3[1][lr] + red3[2][lr] + red3[3][lr]) * inv[r];
  }
  // p -> sT (bf16, swizzled)
#pragma unroll
  for (int n = 0; n < 8; n++)
#pragma unroll
    for (int r = 0; r < 4; r++) {
      int lr = ((lane >> 4) << 2) + r;
      int col = wid * 128 + n * 16 + (lane & 15);
      sT[lr * 512 + (col ^ ((lr & 7) << 3))] = __float2bfloat16(acc[n][r] * inv[r]);
    }
  __syncthreads();

  // ---- stage 3: M = p * Wv (NT with WvT)
  RUN_STAGE(WvT, sT);
#undef RUN_STAGE

  __hip_bfloat16* Mb = Mm + (size_t)b * 262144 + (size_t)(strip * 16) * 512;
#pragma unroll
  for (int n = 0; n < 8; n++)
#pragma unroll
    for (int r = 0; r < 4; r++) {
      int lr = ((lane >> 4) << 2) + r;
      int col = wid * 128 + n * 16 + (lane & 15);
      Mb[(size_t)lr * 512 + col] = __float2bfloat16(acc[n][r]);
    }
}

// ---- out = M x + pb : NN GEMM, B=xh[v,t] via subtiled LDS + ds_read_b64_tr_b16
__global__ __launch_bounds__(256)
void gemm_out_kernel(const __hip_bfloat16* __restrict__ Mall,
                     const __hip_bfloat16* __restrict__ xh,
                     const float* __restrict__ pball,
                     float* __restrict__ out)
{
  __shared__ __align__(16) __hip_bfloat16 sA[2][128 * 64];
  __shared__ __align__(16) __hip_bfloat16 sB[2][64 * 128];

  const int tid = threadIdx.x, lane = tid & 63, wid = tid >> 6;
  const int wr = wid >> 1, wc = wid & 1;

  // XCD chunk of 128 = one batch; tm fastest within chunk -> xh B-panel L2-hot
  const int lin = blockIdx.x + 32 * (blockIdx.y + 4 * blockIdx.z);
  const int lin2 = (lin & 7) * 128 + (lin >> 3);
  const int tm = lin2 & 3;
  const int tn = (lin2 >> 2) & 31;
  const int b  = lin2 >> 7;

  const __hip_bfloat16* Ab = Mall + (size_t)b * 262144 + (size_t)(tm * 128) * 512;
  const __hip_bfloat16* Bb = xh + (size_t)b * ((size_t)CC * TT) + tn * 128;

  f32x4 acc[4][4];
#pragma unroll
  for (int m = 0; m < 4; m++)
#pragma unroll
    for (int n = 0; n < 4; n++) acc[m][n] = (f32x4){0.f, 0.f, 0.f, 0.f};

  auto stage = [&](int buf, int k0) {
#pragma unroll
    for (int i = 0; i < 4; i++) {   // A: [128 k][64 v] swizzled
      int e = tid * 8 + i * 2048;
      int row = e >> 6, colg = (e & 63) ^ ((row & 7) << 3);
      gload_lds16(Ab + (size_t)row * 512 + k0 + colg, &sA[buf][wid * 512 + i * 2048]);
    }
#pragma unroll
    for (int q = 0; q < 4; q++) {   // B: [64 v][128 t] in subtiled layout
      int E = q * 2048 + tid * 8;
      int v = ((E >> 9) << 2) | ((E >> 4) & 3);
      int t = (((E >> 6) & 7) << 4) | (E & 8);
      gload_lds16(Bb + (size_t)(k0 + v) * TT + t, &sB[buf][wid * 512 + q * 2048]);
    }
  };

  const unsigned sB32 =
      (unsigned)(size_t)(__attribute__((address_space(3))) __hip_bfloat16*)&sB[0][0];
  const unsigned btr_lo = sB32 + (lane >> 4) * 2048 + (lane & 15) * 8 + wc * 512;
  const unsigned btr_hi = btr_lo + 8192;

#define COMPUTE(BUF)                                                            \
  {                                                                             \
    _Pragma("unroll")                                                           \
    for (int ks2 = 0; ks2 < 2; ks2++) {                                         \
      bf16x8 af[4]; bf16x4 blo[4], bhi[4];                                      \
      const int kb = ks2 * 32 + (lane >> 4) * 8;                                \
      _Pragma("unroll")                                                         \
      for (int m = 0; m < 4; m++) {                                             \
        int row = wr * 64 + m * 16 + (lane & 15);                               \
        af[m] = *(const bf16x8*)&sA[BUF][row * 64 + (kb ^ ((row & 7) << 3))];   \
      }                                                                         \
      unsigned ab = ks2 ? btr_hi : btr_lo;                                      \
      _Pragma("unroll")                                                         \
      for (int n = 0; n < 4; n++) {                                             \
        asm volatile("ds_read_b64_tr_b16 %0, %1 offset:%2"                      \
                     : "=v"(blo[n]) : "v"(ab), "i"((BUF) * 16384 + n * 128));   \
        asm volatile("ds_read_b64_tr_b16 %0, %1 offset:%2"                      \
                     : "=v"(bhi[n]) : "v"(ab), "i"((BUF) * 16384 + n * 128 + 1024)); \
      }                                                                         \
      asm volatile("s_waitcnt lgkmcnt(0)" ::: "memory");                        \
      __builtin_amdgcn_sched_barrier(0);                                        \
      _Pragma("unroll")                                                         \
      for (int m = 0; m < 4; m++)                                               \
        _Pragma("unroll")                                                       \
        for (int n = 0; n < 4; n++) {                                           \
          bf16x8 b8 = __builtin_shufflevector(blo[n], bhi[n], 0, 1, 2, 3, 4, 5, 6, 7); \
          acc[m][n] = __builtin_amdgcn_mfma_f32_16x16x32_bf16(af[m], b8, acc[m][n], 0, 0, 0); \
        }                                                                       \
    }                                                                           \
  }

  stage(0, 0);
  __syncthreads();
#pragma unroll 1
  for (int s = 0; s < 8; s += 2) {
    if (s + 1 < 8) stage(1, (s + 1) * 64);
    COMPUTE(0);
    __syncthreads();
    if (s + 2 < 8) stage(0, (s + 2) * 64);
    COMPUTE(1);
    __syncthreads();
  }
#undef COMPUTE

  const int rb = tm * 128 + wr * 64 + ((lane >> 4) << 2);
  const int cb = tn * 128 + wc * 64 + (lane & 15);
  float* Cf = out + (size_t)b * ((size_t)CC * TT);
  const float* pbv = pball + b * 512;
#pragma unroll
  for (int m = 0; m < 4; m++)
#pragma unroll
    for (int n = 0; n < 4; n++)
#pragma unroll
      for (int r = 0; r < 4; r++) {
        int row = rb + m * 16 + r, col = cb + n * 16;
        Cf[(size_t)row * TT + col] = acc[m][n][r] + pbv[row];
      }
}

// ----------------------------------------------------------------------------
extern "C" void kernel_launch(void* const* d_in, const int* in_sizes, int n_in,
                              void* d_out, int out_size, void* d_ws, size_t ws_size,
                              hipStream_t stream)
{
  const float* x   = (const float*)d_in[0];
  const float* Wqk = (const float*)d_in[1];
  const float* bqk = (const float*)d_in[2];
  const float* Wv  = (const float*)d_in[3];
  const float* bv  = (const float*)d_in[4];
  float* out = (float*)d_out;

  char* w = (char*)d_ws;
  auto alloc = [&](size_t bytes) {
    void* pp = (void*)w;
    w += (bytes + 255) & ~(size_t)255;
    return pp;
  };
  __hip_bfloat16* xh     = (__hip_bfloat16*)alloc((size_t)BB * CC * TT * 2);
  short*          Gpart  = (short*)alloc((size_t)BB * 4 * CC * CC * 2);
  short*          Gb     = (short*)alloc((size_t)BB * CC * CC * 2);
  __hip_bfloat16* Mm     = (__hip_bfloat16*)alloc((size_t)BB * CC * CC * 2);
  __hip_bfloat16* Wqkh   = (__hip_bfloat16*)alloc((size_t)CC * CC * 2);
  __hip_bfloat16* Wvh    = (__hip_bfloat16*)alloc((size_t)CC * CC * 2);
  __hip_bfloat16* WvT    = (__hip_bfloat16*)alloc((size_t)CC * CC * 2);
  float* sx = (float*)alloc((size_t)BB * CC * 4);
  float* ta = (float*)alloc((size_t)BB * CC * 4);
  float* tb = (float*)alloc((size_t)BB * CC * 4);
  float* pb = (float*)alloc((size_t)BB * CC * 4);

  hipMemsetAsync(sx, 0, (size_t)BB * CC * 4, stream);

  convert_stream_kernel<<<2048, 256, 0, stream>>>(x, xh, sx);
  prep_w_kernel<<<3072, 256, 0, stream>>>(Wqk, Wv, sx, Wqkh, Wvh, WvT, ta, tb);

  const long sXH = (long)CC * TT;
  const long sSq = (long)CC * CC;

  // G = x x^T, split-K=4 (bf16 partials)
  gemm_nt_kernel<128, 128, 0><<<dim3(4, 4, BB * 4), 256, 0, stream>>>(
      xh, sXH, TT, xh, sXH, TT, Gpart, sSq, CC, 1024, 4);
  reduce_g_kernel<<<(BB * CC * CC) / (256 * 8), 256, 0, stream>>>(Gpart, Gb);

  // fused S2+scores+softmax+M (v2)
  middle_kernel<<<256, 256, 0, stream>>>(
      (const __hip_bfloat16*)Gb, Wqkh, Wvh, WvT, bqk, bv, ta, tb, Mm, pb);

  // out = M x + pb (NN, tr_b16 staging of xh)
  gemm_out_kernel<<<dim3(32, 4, 8), 256, 0, stream>>>(Mm, xh, pb, out);
}

// Round 7
// 215.737 us; speedup vs baseline: 1.0201x; 1.0201x over previous
//
#include <hip/hip_runtime.h>
#include <hip/hip_bf16.h>

// Gram-trick pipeline (B=8, C=512, T=4096, SCALE=512):
//   sx[b,c]   = sum_t x[b,c,t]           (fused into streaming convert)
//   G[b]      = x_b x_b^T                (bf16 MFMA, split-K=4 + reduce)   [symmetric]
//   middle v3 : 48-step counted-vmcnt pipeline over 3 chained NT stages:
//               tmp = Wqk_strip*G (G sym); scores = tmp*Wv^T + biases;
//               softmax_v + pb;  M_strip = p*Wv
//   out[b]    = M[b] x_b + pb            (NN: B=xh via subtiled LDS + ds_read_b64_tr_b16)
// All MFMA loops use raw s_barrier + counted s_waitcnt vmcnt(8) (T3/T4):
// panel t+1 stays in flight across the barrier; never drain in main loop.

#define BB 8
#define CC 512
#define TT 4096

typedef __attribute__((ext_vector_type(8))) short bf16x8;
typedef __attribute__((ext_vector_type(4))) short bf16x4;
typedef __attribute__((ext_vector_type(4))) float f32x4;

__device__ __forceinline__ void gload_lds16(const void* g, void* l) {
  __builtin_amdgcn_global_load_lds((const __attribute__((address_space(1))) void*)g,
                                   (__attribute__((address_space(3))) void*)l,
                                   16, 0, 0);
}
__device__ __forceinline__ float bf2f(short u) {
  return __uint_as_float(((unsigned)(unsigned short)u) << 16);
}
__device__ __forceinline__ unsigned short f2bf(float f) {
  return __builtin_bit_cast(unsigned short, __float2bfloat16(f));
}
// raw barrier with compiler fence (no vmcnt drain)
__device__ __forceinline__ void bar_fence() {
  asm volatile("" ::: "memory");
  __builtin_amdgcn_s_barrier();
  asm volatile("" ::: "memory");
}
// LDS-visibility barrier (ds_write -> other-wave read), no vmcnt drain
__device__ __forceinline__ void bar_lds() {
  asm volatile("s_waitcnt lgkmcnt(0)" ::: "memory");
  __builtin_amdgcn_s_barrier();
  asm volatile("" ::: "memory");
}

// ---- streaming convert x -> bf16 [c,t] + fused row-sum ---------------------
__global__ __launch_bounds__(256)
void convert_stream_kernel(const float* __restrict__ x, __hip_bfloat16* __restrict__ xh,
                           float* __restrict__ sx)
{
  const int gid = blockIdx.x * 256 + threadIdx.x;
#pragma unroll
  for (int it = 0; it < 4; it++) {
    const int chunk = it * 524288 + gid;
    const size_t base = (size_t)chunk * 8;
    const float4 a = *(const float4*)&x[base];
    const float4 c = *(const float4*)&x[base + 4];
    bf16x8 h;
    h[0] = (short)f2bf(a.x); h[1] = (short)f2bf(a.y);
    h[2] = (short)f2bf(a.z); h[3] = (short)f2bf(a.w);
    h[4] = (short)f2bf(c.x); h[5] = (short)f2bf(c.y);
    h[6] = (short)f2bf(c.z); h[7] = (short)f2bf(c.w);
    *(bf16x8*)&xh[base] = h;
    float s = ((a.x + a.y) + (a.z + a.w)) + ((c.x + c.y) + (c.z + c.w));
#pragma unroll
    for (int off = 32; off; off >>= 1) s += __shfl_xor(s, off);
    if ((threadIdx.x & 63) == 0) atomicAdd(&sx[chunk >> 9], s);
  }
}

// ---- weights -> bf16 (+WvT) AND ta/tb dot products (grid 3072) -------------
__global__ __launch_bounds__(256)
void prep_w_kernel(const float* __restrict__ Wqk, const float* __restrict__ Wv,
                   const float* __restrict__ sx,
                   __hip_bfloat16* __restrict__ Wqkh, __hip_bfloat16* __restrict__ Wvh,
                   __hip_bfloat16* __restrict__ WvT,
                   float* __restrict__ ta, float* __restrict__ tb)
{
  const int blk = blockIdx.x;
  if (blk < 1024) {
    int i = blk * 256 + threadIdx.x;
    Wqkh[i] = __float2bfloat16(Wqk[i]);
    float wv = Wv[i];
    Wvh[i] = __float2bfloat16(wv);
    WvT[(i & 511) * 512 + (i >> 9)] = __float2bfloat16(wv);
  } else {
    int wid = threadIdx.x >> 6, lane = threadIdx.x & 63;
    int gid = (blk - 1024) * 4 + wid;
    int which = gid >> 12;
    int rem = gid & 4095;
    int b = rem >> 9, j = rem & 511;
    const float* W = which ? Wv : Wqk;
    float s = 0.f;
#pragma unroll
    for (int i2 = 0; i2 < 8; i2++) {
      int c = lane + i2 * 64;
      s += W[j * 512 + c] * sx[b * 512 + c];
    }
#pragma unroll
    for (int off = 32; off; off >>= 1) s += __shfl_xor(s, off);
    if (lane == 0) (which ? tb : ta)[b * 512 + j] = s;
  }
}

// ---- NT GEMM (128x128 only): C = A[M,K] B[N,K]^T, counted-vmcnt pipeline ---
template <int BM, int BN>
__global__ __launch_bounds__(256)
void gemm_nt_kernel(const __hip_bfloat16* __restrict__ A, long strideA, int ldA,
                    const __hip_bfloat16* __restrict__ B, long strideB, int ldB,
                    void* __restrict__ C, long strideC, int ldC,
                    int Kslice, int nslices)
{
  static_assert(BM == 128 && BN == 128, "vmcnt(8) count assumes 8 loads/stage");
  constexpr int FM = BM / 32, FN = BN / 32;
  const int tid = threadIdx.x, lane = tid & 63, wid = tid >> 6;

  const int gx = gridDim.x, gy = gridDim.y;
  const int lin = blockIdx.x + gx * (blockIdx.y + gy * blockIdx.z);
  const int nwg = gx * gy * (int)gridDim.z;
  const int lin2 = (lin & 7) * (nwg >> 3) + (lin >> 3);
  const int tn = lin2 % gx;
  const int r1 = lin2 / gx;
  const int tm = r1 % gy;
  const int z  = r1 / gy;
  const int b  = z / nslices;
  const int ks = z - b * nslices;

  const __hip_bfloat16* Ab = A + (size_t)b * strideA + (size_t)(tm * BM) * ldA + (size_t)ks * Kslice;
  const __hip_bfloat16* Bb = B + (size_t)b * strideB + (size_t)(tn * BN) * ldB + (size_t)ks * Kslice;

  __shared__ __align__(16) __hip_bfloat16 sA[2][BM * 64];
  __shared__ __align__(16) __hip_bfloat16 sB[2][BN * 64];

  const int wr = wid >> 1, wc = wid & 1;

  f32x4 acc[FM][FN];
#pragma unroll
  for (int m = 0; m < FM; m++)
#pragma unroll
    for (int n = 0; n < FN; n++) acc[m][n] = (f32x4){0.f, 0.f, 0.f, 0.f};

  auto stage = [&](int buf, int k0) {
#pragma unroll
    for (int i = 0; i < BM / 32; i++) {
      int e = tid * 8 + i * 2048;
      int row = e >> 6, colg = (e & 63) ^ ((row & 7) << 3);
      gload_lds16(Ab + (size_t)row * ldA + k0 + colg, &sA[buf][wid * 512 + i * 2048]);
    }
#pragma unroll
    for (int i = 0; i < BN / 32; i++) {
      int e = tid * 8 + i * 2048;
      int row = e >> 6, colg = (e & 63) ^ ((row & 7) << 3);
      gload_lds16(Bb + (size_t)row * ldB + k0 + colg, &sB[buf][wid * 512 + i * 2048]);
    }
  };

  const int nsteps = Kslice >> 6;   // 16 for G
  stage(0, 0);
  if (nsteps > 1) stage(1, 64);
#pragma unroll 1
  for (int s = 0; s < nsteps; s++) {
    if (s + 1 < nsteps) asm volatile("s_waitcnt vmcnt(8)" ::: "memory");
    else                asm volatile("s_waitcnt vmcnt(0)" ::: "memory");
    bar_fence();
    const __hip_bfloat16* cA = sA[s & 1];
    const __hip_bfloat16* cB = sB[s & 1];
#pragma unroll
    for (int ks2 = 0; ks2 < 2; ks2++) {
      bf16x8 af[FM], bfv[FN];
      const int kb = ks2 * 32 + (lane >> 4) * 8;
#pragma unroll
      for (int m = 0; m < FM; m++) {
        int row = wr * (BM / 2) + m * 16 + (lane & 15);
        af[m] = *(const bf16x8*)&cA[row * 64 + (kb ^ ((row & 7) << 3))];
      }
#pragma unroll
      for (int n = 0; n < FN; n++) {
        int row = wc * (BN / 2) + n * 16 + (lane & 15);
        bfv[n] = *(const bf16x8*)&cB[row * 64 + (kb ^ ((row & 7) << 3))];
      }
#pragma unroll
      for (int m = 0; m < FM; m++)
#pragma unroll
        for (int n = 0; n < FN; n++)
          acc[m][n] = __builtin_amdgcn_mfma_f32_16x16x32_bf16(af[m], bfv[n], acc[m][n], 0, 0, 0);
    }
    bar_fence();
    if (s + 2 < nsteps) stage(s & 1, (s + 2) << 6);
  }

  const int rb = tm * BM + wr * (BM / 2) + ((lane >> 4) << 2);
  const int cb = tn * BN + wc * (BN / 2) + (lane & 15);
  __hip_bfloat16* Cb = (__hip_bfloat16*)C + (size_t)z * strideC;
#pragma unroll
  for (int m = 0; m < FM; m++)
#pragma unroll
    for (int n = 0; n < FN; n++)
#pragma unroll
      for (int r = 0; r < 4; r++) {
        int row = rb + m * 16 + r, col = cb + n * 16;
        Cb[(size_t)row * ldC + col] = __float2bfloat16(acc[m][n][r]);
      }
}

// ---- reduce split-K bf16 partials -> bf16 G --------------------------------
__global__ __launch_bounds__(256)
void reduce_g_kernel(const short* __restrict__ Gpart, short* __restrict__ Gb)
{
  const int idx = (blockIdx.x * 256 + threadIdx.x) * 8;
  const int b = idx >> 18, i = idx & 262143;
  const short* base = Gpart + ((size_t)(b * 4) << 18) + i;
  float s[8];
#pragma unroll
  for (int q = 0; q < 8; q++) s[q] = 0.f;
#pragma unroll
  for (int ks = 0; ks < 4; ks++) {
    bf16x8 v = *(const bf16x8*)(base + ((size_t)ks << 18));
#pragma unroll
    for (int q = 0; q < 8; q++) s[q] += bf2f(v[q]);
  }
  bf16x8 o;
#pragma unroll
  for (int q = 0; q < 8; q++) o[q] = (short)f2bf(s[q]);
  *(bf16x8*)(Gb + ((size_t)b << 18) + i) = o;
}

// ---- middle v3: 256 blocks, 16-row strips, 48-step counted-vmcnt pipeline --
// Panel stream: t=0..15 from G(b), 16..31 from Wvh, 32..47 from WvT; panel t+1
// always in flight (vmcnt(8)); prefetch crosses stage boundaries so softmax
// time is extra latency cover. sB swizzle: chunk XOR (row>>1)&3  (2-way, free).
__global__ __launch_bounds__(256)
void middle_kernel(const __hip_bfloat16* __restrict__ Gh,
                   const __hip_bfloat16* __restrict__ Wqkh,
                   const __hip_bfloat16* __restrict__ Wvh,
                   const __hip_bfloat16* __restrict__ WvT,
                   const float* __restrict__ bqk, const float* __restrict__ bv,
                   const float* __restrict__ ta, const float* __restrict__ tb,
                   __hip_bfloat16* __restrict__ Mm, float* __restrict__ pb)
{
  __shared__ __align__(16) __hip_bfloat16 sW[16 * 512];
  __shared__ __align__(16) __hip_bfloat16 sT[16 * 512];
  __shared__ __align__(16) __hip_bfloat16 sB[2][512 * 32];
  __shared__ float red1[4][16], red2[4][16], red3[4][16];

  const int tid = threadIdx.x, lane = tid & 63, wid = tid >> 6;
  const int lin = blockIdx.x;
  const int lin2 = (lin & 7) * 32 + (lin >> 3);   // XCD chunk = one batch
  const int strip = lin2 & 31, b = lin2 >> 5;
  const __hip_bfloat16* Ghb = Gh + (size_t)b * 262144;

  // prologue: Wqk strip (4 loads/thread)
#pragma unroll
  for (int i = 0; i < 4; i++) {
    int row = i * 4 + wid;
    int scol = 8 * (lane ^ (row & 7));
    gload_lds16(Wqkh + (size_t)(strip * 16 + row) * 512 + scol, &sW[i * 2048 + wid * 512]);
  }

  auto stageB = [&](int buf, int gt) {
    const __hip_bfloat16* Bsrc = (gt < 16) ? Ghb : (gt < 32 ? Wvh : WvT);
    const int k0 = (gt & 15) * 32;
#pragma unroll
    for (int i = 0; i < 8; i++) {
      int r = i * 64 + wid * 16 + (lane >> 2);
      int scol = k0 + 8 * ((lane & 3) ^ ((r >> 1) & 3));
      gload_lds16(Bsrc + (size_t)r * 512 + scol, &sB[buf][i * 2048 + wid * 512]);
    }
  };

  stageB(0, 0);   // + 8
  stageB(1, 1);   // + 8 (20 outstanding)

  const int arow = lane & 15;
  const int asw = (arow & 7) << 3;
  const int kb = (lane >> 4) * 8;
  f32x4 acc[8];

  auto run16 = [&](int base, const __hip_bfloat16* SX) {
#pragma unroll
    for (int n = 0; n < 8; n++) acc[n] = (f32x4){0.f, 0.f, 0.f, 0.f};
#pragma unroll 1
    for (int t = 0; t < 16; t++) {
      const int gt = base + t;
      if (gt + 1 < 48) asm volatile("s_waitcnt vmcnt(8)" ::: "memory");
      else             asm volatile("s_waitcnt vmcnt(0)" ::: "memory");
      bar_fence();
      const __hip_bfloat16* cB = sB[gt & 1];
      const int kq = t * 32 + kb;
      bf16x8 af = *(const bf16x8*)&SX[arow * 512 + (kq ^ asw)];
#pragma unroll
      for (int n = 0; n < 8; n++) {
        int brow = wid * 128 + n * 16 + (lane & 15);
        bf16x8 bfv = *(const bf16x8*)&cB[brow * 32 + (kb ^ (((brow >> 1) & 3) << 3))];
        acc[n] = __builtin_amdgcn_mfma_f32_16x16x32_bf16(af, bfv, acc[n], 0, 0, 0);
      }
      bar_fence();
      if (gt + 2 < 48) stageB(gt & 1, gt + 2);
    }
  };

  // ---- stage 1: tmp = Wqk_strip * G
  run16(0, sW);
#pragma unroll
  for (int n = 0; n < 8; n++)
#pragma unroll
    for (int r = 0; r < 4; r++) {
      int lr = ((lane >> 4) << 2) + r;
      int col = wid * 128 + n * 16 + (lane & 15);
      sT[lr * 512 + (col ^ ((lr & 7) << 3))] = __float2bfloat16(acc[n][r]);
    }
  bar_lds();

  // ---- stage 2: scores = tmp * Wv^T
  run16(16, sT);

  const float* tab = ta + b * 512;
  const float* tbb = tb + b * 512;
  float bvc[8], tbc[8];
#pragma unroll
  for (int n = 0; n < 8; n++) {
    int col = wid * 128 + n * 16 + (lane & 15);
    bvc[n] = bv[col]; tbc[n] = tbb[col];
  }
  float bq[4], tar[4];
#pragma unroll
  for (int r = 0; r < 4; r++) {
    int gr = strip * 16 + ((lane >> 4) << 2) + r;
    bq[r] = bqk[gr]; tar[r] = tab[gr];
  }
#pragma unroll
  for (int n = 0; n < 8; n++)
#pragma unroll
    for (int r = 0; r < 4; r++)
      acc[n][r] = (acc[n][r] + bq[r] * tbc[n] + tar[r] * bvc[n]
                   + 4096.0f * bq[r] * bvc[n]) * (1.0f / 512.0f);

  // softmax over v (16-lane shfl + cross-wave via LDS)
#pragma unroll
  for (int r = 0; r < 4; r++) {
    float v = acc[0][r];
#pragma unroll
    for (int n = 1; n < 8; n++) v = fmaxf(v, acc[n][r]);
#pragma unroll
    for (int off = 1; off < 16; off <<= 1) v = fmaxf(v, __shfl_xor(v, off));
    if ((lane & 15) == 0) red1[wid][((lane >> 4) << 2) + r] = v;
  }
  bar_lds();
  float mx[4];
#pragma unroll
  for (int r = 0; r < 4; r++) {
    int lr = ((lane >> 4) << 2) + r;
    mx[r] = fmaxf(fmaxf(red1[0][lr], red1[1][lr]), fmaxf(red1[2][lr], red1[3][lr]));
  }
#pragma unroll
  for (int r = 0; r < 4; r++) {
    float s = 0.f, pp = 0.f;
#pragma unroll
    for (int n = 0; n < 8; n++) {
      float e = __expf(acc[n][r] - mx[r]);
      acc[n][r] = e;
      s += e; pp += e * bvc[n];
    }
#pragma unroll
    for (int off = 1; off < 16; off <<= 1) { s += __shfl_xor(s, off); pp += __shfl_xor(pp, off); }
    if ((lane & 15) == 0) {
      red2[wid][((lane >> 4) << 2) + r] = s;
      red3[wid][((lane >> 4) << 2) + r] = pp;
    }
  }
  bar_lds();
  float inv[4];
#pragma unroll
  for (int r = 0; r < 4; r++) {
    int lr = ((lane >> 4) << 2) + r;
    float sum = red2[0][lr] + red2[1][lr] + red2[2][lr] + red2[3][lr];
    inv[r] = 1.0f / sum;
    if (wid == 0 && (lane & 15) == 0)
      pb[b * 512 + strip * 16 + lr] =
          (red3[0][lr] + red3[1][lr] + red3[2][lr] + red3[3][lr]) * inv[r];
  }
#pragma unroll
  for (int n = 0; n < 8; n++)
#pragma unroll
    for (int r = 0; r < 4; r++) {
      int lr = ((lane >> 4) << 2) + r;
      int col = wid * 128 + n * 16 + (lane & 15);
      sT[lr * 512 + (col ^ ((lr & 7) << 3))] = __float2bfloat16(acc[n][r] * inv[r]);
    }
  bar_lds();

  // ---- stage 3: M = p * Wv (NT with WvT)
  run16(32, sT);

  __hip_bfloat16* Mb = Mm + (size_t)b * 262144 + (size_t)(strip * 16) * 512;
#pragma unroll
  for (int n = 0; n < 8; n++)
#pragma unroll
    for (int r = 0; r < 4; r++) {
      int lr = ((lane >> 4) << 2) + r;
      int col = wid * 128 + n * 16 + (lane & 15);
      Mb[(size_t)lr * 512 + col] = __float2bfloat16(acc[n][r]);
    }
}

// ---- out = M x + pb : NN GEMM, B=xh via subtiled LDS + ds_read_b64_tr_b16 --
__global__ __launch_bounds__(256)
void gemm_out_kernel(const __hip_bfloat16* __restrict__ Mall,
                     const __hip_bfloat16* __restrict__ xh,
                     const float* __restrict__ pball,
                     float* __restrict__ out)
{
  __shared__ __align__(16) __hip_bfloat16 sA[2][128 * 64];
  __shared__ __align__(16) __hip_bfloat16 sB[2][64 * 128];

  const int tid = threadIdx.x, lane = tid & 63, wid = tid >> 6;
  const int wr = wid >> 1, wc = wid & 1;

  const int lin = blockIdx.x + 32 * (blockIdx.y + 4 * blockIdx.z);
  const int lin2 = (lin & 7) * 128 + (lin >> 3);
  const int tm = lin2 & 3;
  const int tn = (lin2 >> 2) & 31;
  const int b  = lin2 >> 7;

  const __hip_bfloat16* Ab = Mall + (size_t)b * 262144 + (size_t)(tm * 128) * 512;
  const __hip_bfloat16* Bb = xh + (size_t)b * ((size_t)CC * TT) + tn * 128;

  f32x4 acc[4][4];
#pragma unroll
  for (int m = 0; m < 4; m++)
#pragma unroll
    for (int n = 0; n < 4; n++) acc[m][n] = (f32x4){0.f, 0.f, 0.f, 0.f};

  auto stage = [&](int buf, int k0) {
#pragma unroll
    for (int i = 0; i < 4; i++) {
      int e = tid * 8 + i * 2048;
      int row = e >> 6, colg = (e & 63) ^ ((row & 7) << 3);
      gload_lds16(Ab + (size_t)row * 512 + k0 + colg, &sA[buf][wid * 512 + i * 2048]);
    }
#pragma unroll
    for (int q = 0; q < 4; q++) {
      int E = q * 2048 + tid * 8;
      int v = ((E >> 9) << 2) | ((E >> 4) & 3);
      int t = (((E >> 6) & 7) << 4) | (E & 8);
      gload_lds16(Bb + (size_t)(k0 + v) * TT + t, &sB[buf][wid * 512 + q * 2048]);
    }
  };

  const unsigned sB32 =
      (unsigned)(size_t)(__attribute__((address_space(3))) __hip_bfloat16*)&sB[0][0];
  const unsigned btr_lo = sB32 + (lane >> 4) * 2048 + (lane & 15) * 8 + wc * 512;
  const unsigned btr_hi = btr_lo + 8192;

#define COMPUTE(BUF)                                                            \
  {                                                                             \
    _Pragma("unroll")                                                           \
    for (int ks2 = 0; ks2 < 2; ks2++) {                                         \
      bf16x8 af[4]; bf16x4 blo[4], bhi[4];                                      \
      const int kb = ks2 * 32 + (lane >> 4) * 8;                                \
      _Pragma("unroll")                                                         \
      for (int m = 0; m < 4; m++) {                                             \
        int row = wr * 64 + m * 16 + (lane & 15);                               \
        af[m] = *(const bf16x8*)&sA[BUF][row * 64 + (kb ^ ((row & 7) << 3))];   \
      }                                                                         \
      unsigned ab = ks2 ? btr_hi : btr_lo;                                      \
      _Pragma("unroll")                                                         \
      for (int n = 0; n < 4; n++) {                                             \
        asm volatile("ds_read_b64_tr_b16 %0, %1 offset:%2"                      \
                     : "=v"(blo[n]) : "v"(ab), "i"((BUF) * 16384 + n * 128));   \
        asm volatile("ds_read_b64_tr_b16 %0, %1 offset:%2"                      \
                     : "=v"(bhi[n]) : "v"(ab), "i"((BUF) * 16384 + n * 128 + 1024)); \
      }                                                                         \
      asm volatile("s_waitcnt lgkmcnt(0)" ::: "memory");                        \
      __builtin_amdgcn_sched_barrier(0);                                        \
      _Pragma("unroll")                                                         \
      for (int m = 0; m < 4; m++)                                               \
        _Pragma("unroll")                                                       \
        for (int n = 0; n < 4; n++) {                                           \
          bf16x8 b8 = __builtin_shufflevector(blo[n], bhi[n], 0, 1, 2, 3, 4, 5, 6, 7); \
          acc[m][n] = __builtin_amdgcn_mfma_f32_16x16x32_bf16(af[m], b8, acc[m][n], 0, 0, 0); \
        }                                                                       \
    }                                                                           \
  }

  stage(0, 0);
  stage(1, 64);
#pragma unroll 1
  for (int s = 0; s < 8; s += 2) {
    asm volatile("s_waitcnt vmcnt(8)" ::: "memory");   // s+1<8 always here
    bar_fence();
    COMPUTE(0);
    bar_fence();
    if (s + 2 < 8) stage(0, (s + 2) * 64);
    if (s + 2 < 8) asm volatile("s_waitcnt vmcnt(8)" ::: "memory");
    else           asm volatile("s_waitcnt vmcnt(0)" ::: "memory");
    bar_fence();
    COMPUTE(1);
    bar_fence();
    if (s + 3 < 8) stage(1, (s + 3) * 64);
  }
#undef COMPUTE

  const int rb = tm * 128 + wr * 64 + ((lane >> 4) << 2);
  const int cb = tn * 128 + wc * 64 + (lane & 15);
  float* Cf = out + (size_t)b * ((size_t)CC * TT);
  const float* pbv = pball + b * 512;
#pragma unroll
  for (int m = 0; m < 4; m++)
#pragma unroll
    for (int n = 0; n < 4; n++)
#pragma unroll
      for (int r = 0; r < 4; r++) {
        int row = rb + m * 16 + r, col = cb + n * 16;
        Cf[(size_t)row * TT + col] = acc[m][n][r] + pbv[row];
      }
}

// ----------------------------------------------------------------------------
extern "C" void kernel_launch(void* const* d_in, const int* in_sizes, int n_in,
                              void* d_out, int out_size, void* d_ws, size_t ws_size,
                              hipStream_t stream)
{
  const float* x   = (const float*)d_in[0];
  const float* Wqk = (const float*)d_in[1];
  const float* bqk = (const float*)d_in[2];
  const float* Wv  = (const float*)d_in[3];
  const float* bv  = (const float*)d_in[4];
  float* out = (float*)d_out;

  char* w = (char*)d_ws;
  auto alloc = [&](size_t bytes) {
    void* pp = (void*)w;
    w += (bytes + 255) & ~(size_t)255;
    return pp;
  };
  __hip_bfloat16* xh     = (__hip_bfloat16*)alloc((size_t)BB * CC * TT * 2);
  short*          Gpart  = (short*)alloc((size_t)BB * 4 * CC * CC * 2);
  short*          Gb     = (short*)alloc((size_t)BB * CC * CC * 2);
  __hip_bfloat16* Mm     = (__hip_bfloat16*)alloc((size_t)BB * CC * CC * 2);
  __hip_bfloat16* Wqkh   = (__hip_bfloat16*)alloc((size_t)CC * CC * 2);
  __hip_bfloat16* Wvh    = (__hip_bfloat16*)alloc((size_t)CC * CC * 2);
  __hip_bfloat16* WvT    = (__hip_bfloat16*)alloc((size_t)CC * CC * 2);
  float* sx = (float*)alloc((size_t)BB * CC * 4);
  float* ta = (float*)alloc((size_t)BB * CC * 4);
  float* tb = (float*)alloc((size_t)BB * CC * 4);
  float* pb = (float*)alloc((size_t)BB * CC * 4);

  hipMemsetAsync(sx, 0, (size_t)BB * CC * 4, stream);

  convert_stream_kernel<<<2048, 256, 0, stream>>>(x, xh, sx);
  prep_w_kernel<<<3072, 256, 0, stream>>>(Wqk, Wv, sx, Wqkh, Wvh, WvT, ta, tb);

  const long sXH = (long)CC * TT;
  const long sSq = (long)CC * CC;

  // G = x x^T, split-K=4 (bf16 partials)
  gemm_nt_kernel<128, 128><<<dim3(4, 4, BB * 4), 256, 0, stream>>>(
      xh, sXH, TT, xh, sXH, TT, Gpart, sSq, CC, 1024, 4);
  reduce_g_kernel<<<(BB * CC * CC) / (256 * 8), 256, 0, stream>>>(Gpart, Gb);

  // fused S2+scores+softmax+M (v3, counted-vmcnt pipeline)
  middle_kernel<<<256, 256, 0, stream>>>(
      (const __hip_bfloat16*)Gb, Wqkh, Wvh, WvT, bqk, bv, ta, tb, Mm, pb);

  // out = M x + pb (NN, tr_b16 staging of xh)
  gemm_out_kernel<<<dim3(32, 4, 8), 256, 0, stream>>>(Mm, xh, pb, out);
}